// Round 4
// baseline (355.527 us; speedup 1.0000x reference)
//
#include <hip/hip_runtime.h>

// ---------------------------------------------------------------------------
// AGNN: h = relu(x@W1^T+b1); 4x [ h = relu(agnn(h)) ]; out = h@W2^T+b2
// N=100000, E=1600000, IN=128, HID=OUT=64, float32 in/out.
// Between layers: xn = h/(||h||+eps) stored FP16 (128 B/row) + nrm f32.
//   p = exp2( dot(xn_i * log2e, xn_j) );  out_i = sum p * nrm_j * xn_j / sum p
// Round 4: agnn rewritten EDGE-PER-LANE (round-3 analysis: 15.6 cyc/edge was
// the per-edge serial chain of 3 shfl_xor + 4 dep fdot2 + exp2; loads were
// already hidden).  New structure:
//   wave = 8 nodes x 8 lanes; batch = 8 edges/node (64 rows).
//   global_load_lds stages 64 rows x 128B coalesced into per-wave LDS with
//   XOR chunk swizzle (phys = logical ^ (row&7)) applied via the GLOBAL
//   source address (linear LDS dest is required by global_load_lds).
//   Each lane: full 64-dim dot in-register (8 ds_read_b128 + 32 fdot2),
//   private exp2, private f16 accumulation. NO per-edge cross-lane ops.
//   Merge once per node: acc dump to LDS + 8-row chunk sum + 3 shfl den.
//   All LDS per-wave private -> zero __syncthreads.
// gemm1/gemm2 (512 thr, prefetch), rowptr scan, 1024-seg sort unchanged.
// ---------------------------------------------------------------------------

typedef _Float16 h2 __attribute__((ext_vector_type(2)));

union U4H { uint4 u; h2 h[4]; };
union U2H { uint2 u; h2 h[2]; };

#define DEV_INLINE __device__ __forceinline__

DEV_INLINE h2 mkh2(float a, float b) {
    h2 r; r.x = (_Float16)a; r.y = (_Float16)b; return r;
}

// ptr[i] = lower_bound(row, i). Thread e covers i in (row[e-1], row[e]].
__global__ __launch_bounds__(256) void build_rowptr_scan(const int* __restrict__ row,
                                                         int* __restrict__ ptr,
                                                         int N, int E) {
    int e = blockIdx.x * blockDim.x + threadIdx.x;
    if (e >= E) return;
    const int r1 = row[e];
    const int r0 = (e == 0) ? -1 : row[e - 1];
    for (int i = r0 + 1; i <= r1; ++i) ptr[i] = e;
    if (e == E - 1) {
        for (int i = r1 + 1; i <= N; ++i) ptr[i] = E;
    }
}

// Segment-local counting sort by degree. One 1024-thread block per 1024-node
// segment (1 node per thread); 256-bucket LDS histogram + 8-step scan.
#define PSEG 1024
__global__ __launch_bounds__(1024) void build_perm_seg(const int* __restrict__ ptr,
                                                       int* __restrict__ perm,
                                                       int N) {
    __shared__ int hist[256];
    __shared__ int tmp[256];
    const int t    = threadIdx.x;
    const int base = blockIdx.x * PSEG;
    const int end  = (base + PSEG < N) ? base + PSEG : N;
    const int cnt  = end - base;

    if (t < 256) hist[t] = 0;
    __syncthreads();

    int d = -1;
    if (t < cnt) {
        d = ptr[base + t + 1] - ptr[base + t];
        if (d > 255) d = 255;
        atomicAdd(&hist[d], 1);
    }
    __syncthreads();

    int h0 = (t < 256) ? hist[t] : 0;
    int* src = hist; int* dst = tmp;
    for (int off = 1; off < 256; off <<= 1) {
        if (t < 256) dst[t] = src[t] + (t >= off ? src[t - off] : 0);
        __syncthreads();
        int* tt = src; src = dst; dst = tt;
    }
    if (t < 256) src[t] -= h0;
    __syncthreads();

    if (t < cnt) {
        int pos = base + atomicAdd(&src[d], 1);
        perm[pos] = base + t;
    }
}

// r = relu(x[i,:128]@W1^T + b1); xn[i]=f16(r/(||r||+eps)); nrm[i]=||r||+eps
// 512 threads, tile 128 nodes x 64 outs, thread = 4 nodes x 4 outs.
__global__ __launch_bounds__(512) void gemm1_relu(const float* __restrict__ x,
                                                  const float* __restrict__ W1,
                                                  const float* __restrict__ b1,
                                                  unsigned short* __restrict__ xn,
                                                  float* __restrict__ nrm,
                                                  int N) {
    __shared__ __align__(16) float Wt[32 * 64];    // 8 KiB
    __shared__ __align__(16) float xT[32 * 128];   // 16 KiB
    const int tid  = threadIdx.x;
    const int tx   = tid & 15;
    const int ty   = tid >> 4;
    const int base = blockIdx.x * 128;

    const float4* W4  = (const float4*)W1;
    const float4* x4p = (const float4*)x;

    const int wO  = tid & 63;
    const int wK4 = tid >> 6;
    const int mA  = tid & 127;
    const int kA  = tid >> 7;
    const int mB  = mA;
    const int kB  = kA + 4;
    const int nodeA = base + mA;

    float4 wv, xa_, xb_;
    wv = W4[wO * 32 + wK4];
    xa_ = make_float4(0.f, 0.f, 0.f, 0.f);
    xb_ = xa_;
    if (nodeA < N) {
        xa_ = x4p[(size_t)nodeA * 32 + kA];
        xb_ = x4p[(size_t)nodeA * 32 + kB];
    }

    float4 b4 = ((const float4*)b1)[tx];
    float4 acc[4];
    acc[0] = b4; acc[1] = b4; acc[2] = b4; acc[3] = b4;

    for (int c = 0; c < 4; ++c) {
        Wt[(4 * wK4 + 0) * 64 + wO] = wv.x;
        Wt[(4 * wK4 + 1) * 64 + wO] = wv.y;
        Wt[(4 * wK4 + 2) * 64 + wO] = wv.z;
        Wt[(4 * wK4 + 3) * 64 + wO] = wv.w;
        xT[(4 * kA + 0) * 128 + mA] = xa_.x;
        xT[(4 * kA + 1) * 128 + mA] = xa_.y;
        xT[(4 * kA + 2) * 128 + mA] = xa_.z;
        xT[(4 * kA + 3) * 128 + mA] = xa_.w;
        xT[(4 * kB + 0) * 128 + mB] = xb_.x;
        xT[(4 * kB + 1) * 128 + mB] = xb_.y;
        xT[(4 * kB + 2) * 128 + mB] = xb_.z;
        xT[(4 * kB + 3) * 128 + mB] = xb_.w;
        __syncthreads();

        if (c < 3) {
            const int ko = (c + 1) * 8;
            wv = W4[wO * 32 + ko + wK4];
            if (nodeA < N) {
                xa_ = x4p[(size_t)nodeA * 32 + ko + kA];
                xb_ = x4p[(size_t)nodeA * 32 + ko + kB];
            }
        }

#pragma unroll 4
        for (int k = 0; k < 32; ++k) {
            const float4 w4 = *(const float4*)&Wt[k * 64 + 4 * tx];
            const float4 xv = *(const float4*)&xT[k * 128 + 4 * ty];
            acc[0].x = fmaf(xv.x, w4.x, acc[0].x);
            acc[0].y = fmaf(xv.x, w4.y, acc[0].y);
            acc[0].z = fmaf(xv.x, w4.z, acc[0].z);
            acc[0].w = fmaf(xv.x, w4.w, acc[0].w);
            acc[1].x = fmaf(xv.y, w4.x, acc[1].x);
            acc[1].y = fmaf(xv.y, w4.y, acc[1].y);
            acc[1].z = fmaf(xv.y, w4.z, acc[1].z);
            acc[1].w = fmaf(xv.y, w4.w, acc[1].w);
            acc[2].x = fmaf(xv.z, w4.x, acc[2].x);
            acc[2].y = fmaf(xv.z, w4.y, acc[2].y);
            acc[2].z = fmaf(xv.z, w4.z, acc[2].z);
            acc[2].w = fmaf(xv.z, w4.w, acc[2].w);
            acc[3].x = fmaf(xv.w, w4.x, acc[3].x);
            acc[3].y = fmaf(xv.w, w4.y, acc[3].y);
            acc[3].z = fmaf(xv.w, w4.z, acc[3].z);
            acc[3].w = fmaf(xv.w, w4.w, acc[3].w);
        }
        if (c < 3) __syncthreads();
    }

#pragma unroll
    for (int mm = 0; mm < 4; ++mm) {
        float4 r = acc[mm];
        r.x = fmaxf(r.x, 0.f); r.y = fmaxf(r.y, 0.f);
        r.z = fmaxf(r.z, 0.f); r.w = fmaxf(r.w, 0.f);
        float s = fmaf(r.x, r.x, fmaf(r.y, r.y, fmaf(r.z, r.z, r.w * r.w)));
        s += __shfl_xor(s, 1, 64);
        s += __shfl_xor(s, 2, 64);
        s += __shfl_xor(s, 4, 64);
        s += __shfl_xor(s, 8, 64);
        const float nn  = sqrtf(s) + 1e-12f;
        const float inv = 1.f / nn;
        int node = base + 4 * ty + mm;
        if (node < N) {
            U2H pk;
            pk.h[0] = mkh2(r.x * inv, r.y * inv);
            pk.h[1] = mkh2(r.z * inv, r.w * inv);
            *(uint2*)&xn[(size_t)node * 64 + 4 * tx] = pk.u;
            if (tx == mm) nrm[node] = nn;
        }
    }
}

// -------------------- agnn: edge-per-lane --------------------
// wave = 8 nodes x 8 lanes. Lane l: node q = l>>3, slot m = l&7.
// LDS per wave: 64 rows x 128B (8 KiB). Row r's logical chunk k stored at
// physical slot (k ^ (r&7)) -> conflict-free-ish stride-128B per-lane reads.
// Staging instr k (k=0..7): LDS dest = base + k*1024 + lane*16 (linear),
//   covers (row = 8k + q, phys slot = m) -> logical chunk (m ^ q) of the
//   (b*8 + q)-th edge of NODE k. Global source address carries the swizzle.
__global__ __launch_bounds__(256) void agnn_layer(const uint4* __restrict__ xn4,
                                                  const float* __restrict__ nrm,
                                                  const int* __restrict__ ptr,
                                                  const int* __restrict__ col,
                                                  const int* __restrict__ perm,
                                                  uint4* __restrict__ xo4,
                                                  float* __restrict__ nrmo,
                                                  int N, int E) {
    __shared__ uint4 lds_all[4 * 512];          // 4 waves x 8 KiB
    const int tid  = threadIdx.x;
    const int wid  = tid >> 6;
    const int lane = tid & 63;
    const int q    = lane >> 3;                 // node within octet
    const int m    = lane & 7;                  // edge slot / chunk index
    uint4* W = lds_all + wid * 512;

    const int octet = blockIdx.x * 4 + wid;
    const int slot  = octet * 8 + q;
    const bool slotOK = slot < N;
    const int nid = slotOK ? perm[slot] : 0;
    const int p0  = ptr[nid];
    const int p1  = ptr[nid + 1];
    const int deg = slotOK ? (p1 - p0) : 0;

    // wave-uniform batch count = max degree over the octet
    int md = deg;
    md = max(md, __shfl_xor(md, 1, 64));
    md = max(md, __shfl_xor(md, 2, 64));
    md = max(md, __shfl_xor(md, 4, 64));
    md = max(md, __shfl_xor(md, 8, 64));
    md = max(md, __shfl_xor(md, 16, 64));
    md = max(md, __shfl_xor(md, 32, 64));
    const int nbatch = (md + 7) >> 3;

    // p0 of node k broadcast to all lanes (node k lives at lane 8k)
    int p0a[8];
#pragma unroll
    for (int k = 0; k < 8; ++k) p0a[k] = __shfl(p0, 8 * k, 64);

    // own node's row, pre-scaled by log2(e)
    U4H hi[8];
    {
        const unsigned br = (unsigned)nid * 8u;
#pragma unroll
        for (int k = 0; k < 8; ++k) hi[k].u = xn4[br + k];
        const _Float16 L2E = (_Float16)1.4426950408889634f;
        h2 l2 = {L2E, L2E};
#pragma unroll
        for (int k = 0; k < 8; ++k) {
            hi[k].h[0] *= l2; hi[k].h[1] *= l2;
            hi[k].h[2] *= l2; hi[k].h[3] *= l2;
        }
    }

    float den = 0.f;
    U4H acc[8];
#pragma unroll
    for (int k = 0; k < 8; ++k) {
        acc[k].h[0] = mkh2(0.f, 0.f); acc[k].h[1] = mkh2(0.f, 0.f);
        acc[k].h[2] = mkh2(0.f, 0.f); acc[k].h[3] = mkh2(0.f, 0.f);
    }

    const int rowBase = lane * 8;               // uint4 index of own row

    for (int b = 0; b < nbatch; ++b) {
        // ---- stage 64 rows (8 per node) into LDS, swizzled via source ----
#pragma unroll
        for (int k = 0; k < 8; ++k) {
            int e = p0a[k] + b * 8 + q;
            e = min(e, E - 1);
            const int j = col[e];               // row for (node k, slot q)
            const uint4* src = xn4 + (unsigned)j * 8u + (unsigned)(m ^ q);
            __builtin_amdgcn_global_load_lds((const unsigned int*)src,
                                             (unsigned int*)(W + k * 64),
                                             16, 0, 0);
        }

        // ---- own edge: index + nrm (overlaps with staging) ----
        const bool valid = (b * 8 + m) < deg;
        int eo = p0 + b * 8 + m;
        eo = min(eo, E - 1);
        const int jown = col[eo];
        const float nj = nrm[jown];

        asm volatile("s_waitcnt vmcnt(0)" ::: "memory");

        // ---- full 64-dim dot in-register (no cross-lane) ----
        float s0 = 0.f, s1 = 0.f, s2 = 0.f, s3 = 0.f;
#pragma unroll
        for (int k = 0; k < 8; ++k) {
            U4H rv; rv.u = W[rowBase + (k ^ m)];
            s0 = __builtin_amdgcn_fdot2(hi[k].h[0], rv.h[0], s0, false);
            s1 = __builtin_amdgcn_fdot2(hi[k].h[1], rv.h[1], s1, false);
            s2 = __builtin_amdgcn_fdot2(hi[k].h[2], rv.h[2], s2, false);
            s3 = __builtin_amdgcn_fdot2(hi[k].h[3], rv.h[3], s3, false);
        }
        const float s = (s0 + s1) + (s2 + s3);
        const float p = valid ? exp2f(s) : 0.f;
        den += p;
        const _Float16 wh = (_Float16)(p * nj);
        h2 w2 = {wh, wh};

        // ---- private weighted accumulation ----
#pragma unroll
        for (int k = 0; k < 8; ++k) {
            U4H rv; rv.u = W[rowBase + (k ^ m)];
            acc[k].h[0] += w2 * rv.h[0];
            acc[k].h[1] += w2 * rv.h[1];
            acc[k].h[2] += w2 * rv.h[2];
            acc[k].h[3] += w2 * rv.h[3];
        }
    }

    // ---- merge: dump acc (staging buffer is dead), chunk-sum per node ----
#pragma unroll
    for (int k = 0; k < 8; ++k) W[rowBase + (k ^ m)] = acc[k].u;

    // lane l produces output chunk m of node q: sum logical chunk m over
    // rows 8q..8q+7 (row 8q+t holds chunk m at phys slot m^t)
    U4H sum;
    sum.h[0] = mkh2(0.f, 0.f); sum.h[1] = mkh2(0.f, 0.f);
    sum.h[2] = mkh2(0.f, 0.f); sum.h[3] = mkh2(0.f, 0.f);
#pragma unroll
    for (int t = 0; t < 8; ++t) {
        U4H v; v.u = W[(8 * q + t) * 8 + (m ^ t)];
        sum.h[0] += v.h[0]; sum.h[1] += v.h[1];
        sum.h[2] += v.h[2]; sum.h[3] += v.h[3];
    }

    // den over the node's 8 lanes
    den += __shfl_xor(den, 1, 64);
    den += __shfl_xor(den, 2, 64);
    den += __shfl_xor(den, 4, 64);

    const float id = 1.f / fmaxf(den, 1e-12f);
    float o[8];
#pragma unroll
    for (int t = 0; t < 4; ++t) {
        o[2 * t]     = fmaxf((float)sum.h[t].x * id, 0.f);
        o[2 * t + 1] = fmaxf((float)sum.h[t].y * id, 0.f);
    }

    float s2 = 0.f;
#pragma unroll
    for (int t = 0; t < 8; ++t) s2 = fmaf(o[t], o[t], s2);
    s2 += __shfl_xor(s2, 1, 64);
    s2 += __shfl_xor(s2, 2, 64);
    s2 += __shfl_xor(s2, 4, 64);
    const float nn  = sqrtf(s2) + 1e-12f;
    const float inv = 1.f / nn;

    if (slotOK) {
        U4H ov;
        ov.h[0] = mkh2(o[0] * inv, o[1] * inv);
        ov.h[1] = mkh2(o[2] * inv, o[3] * inv);
        ov.h[2] = mkh2(o[4] * inv, o[5] * inv);
        ov.h[3] = mkh2(o[6] * inv, o[7] * inv);
        xo4[(unsigned)nid * 8u + m] = ov.u;
        if (m == 0) nrmo[nid] = nn;
    }
}

// out[i,:64] = (xn[i]*nrm[i]) @ W2^T + b2   (f32 out)
// 512 threads, tile 128 nodes x 64 outs, thread = 4 nodes x 4 outs.
__global__ __launch_bounds__(512) void gemm2(const unsigned short* __restrict__ xn,
                                             const float* __restrict__ nrm,
                                             const float* __restrict__ W2,
                                             const float* __restrict__ b2,
                                             float* __restrict__ out,
                                             int N) {
    __shared__ __align__(16) float Wt[64 * 64];
    __shared__ __align__(16) float xT[64 * 128];
    const int tid  = threadIdx.x;
    const int tx   = tid & 15;
    const int ty   = tid >> 4;
    const int base = blockIdx.x * 128;

    {
        const float4* W4 = (const float4*)W2;
#pragma unroll
        for (int it = 0; it < 2; ++it) {
            int idx = tid + it * 512;
            int o = idx & 63, k4 = idx >> 6;
            float4 v = W4[o * 16 + k4];
            Wt[(4 * k4 + 0) * 64 + o] = v.x;
            Wt[(4 * k4 + 1) * 64 + o] = v.y;
            Wt[(4 * k4 + 2) * 64 + o] = v.z;
            Wt[(4 * k4 + 3) * 64 + o] = v.w;
        }
        const uint2* x2 = (const uint2*)xn;
#pragma unroll
        for (int it = 0; it < 4; ++it) {
            int idx = tid + it * 512;
            int mm = idx & 127, k4 = idx >> 7;
            int node = base + mm;
            U2H v; v.u = make_uint2(0u, 0u);
            float nn = 0.f;
            if (node < N) { v.u = x2[(size_t)node * 16 + k4]; nn = nrm[node]; }
            xT[(4 * k4 + 0) * 128 + mm] = (float)v.h[0].x * nn;
            xT[(4 * k4 + 1) * 128 + mm] = (float)v.h[0].y * nn;
            xT[(4 * k4 + 2) * 128 + mm] = (float)v.h[1].x * nn;
            xT[(4 * k4 + 3) * 128 + mm] = (float)v.h[1].y * nn;
        }
    }
    __syncthreads();

    float4 b4 = ((const float4*)b2)[tx];
    float4 acc[4];
    acc[0] = b4; acc[1] = b4; acc[2] = b4; acc[3] = b4;

#pragma unroll 4
    for (int k = 0; k < 64; ++k) {
        const float4 w4 = *(const float4*)&Wt[k * 64 + 4 * tx];
        const float4 xv = *(const float4*)&xT[k * 128 + 4 * ty];
        acc[0].x = fmaf(xv.x, w4.x, acc[0].x);
        acc[0].y = fmaf(xv.x, w4.y, acc[0].y);
        acc[0].z = fmaf(xv.x, w4.z, acc[0].z);
        acc[0].w = fmaf(xv.x, w4.w, acc[0].w);
        acc[1].x = fmaf(xv.y, w4.x, acc[1].x);
        acc[1].y = fmaf(xv.y, w4.y, acc[1].y);
        acc[1].z = fmaf(xv.y, w4.z, acc[1].z);
        acc[1].w = fmaf(xv.y, w4.w, acc[1].w);
        acc[2].x = fmaf(xv.z, w4.x, acc[2].x);
        acc[2].y = fmaf(xv.z, w4.y, acc[2].y);
        acc[2].z = fmaf(xv.z, w4.z, acc[2].z);
        acc[2].w = fmaf(xv.z, w4.w, acc[2].w);
        acc[3].x = fmaf(xv.w, w4.x, acc[3].x);
        acc[3].y = fmaf(xv.w, w4.y, acc[3].y);
        acc[3].z = fmaf(xv.w, w4.z, acc[3].z);
        acc[3].w = fmaf(xv.w, w4.w, acc[3].w);
    }

#pragma unroll
    for (int mm = 0; mm < 4; ++mm) {
        int node = base + 4 * ty + mm;
        if (node < N) *(float4*)&out[(size_t)node * 64 + 4 * tx] = acc[mm];
    }
}

extern "C" void kernel_launch(void* const* d_in, const int* in_sizes, int n_in,
                              void* d_out, int out_size, void* d_ws, size_t ws_size,
                              hipStream_t stream) {
    const float* x   = (const float*)d_in[0];
    const int*   row = (const int*)d_in[1];
    const int*   col = (const int*)d_in[2];
    const float* W1  = (const float*)d_in[3];
    const float* b1  = (const float*)d_in[4];
    const float* W2  = (const float*)d_in[5];
    const float* b2  = (const float*)d_in[6];
    float* out = (float*)d_out;

    const int N = in_sizes[0] / 128;
    const int E = in_sizes[1];

    char* ws = (char*)d_ws;
    size_t off = 0;
    unsigned short* ha = (unsigned short*)(ws + off); off += (size_t)N * 64 * 2;
    unsigned short* hb = (unsigned short*)(ws + off); off += (size_t)N * 64 * 2;
    float* na_  = (float*)(ws + off); off += (size_t)N * sizeof(float);
    float* nb_  = (float*)(ws + off); off += (size_t)N * sizeof(float);
    int*   ptr  = (int*)  (ws + off); off += (size_t)(N + 1) * sizeof(int);
    off = (off + 15) & ~(size_t)15;
    int*   perm = (int*)  (ws + off); off += (size_t)N * sizeof(int);
    (void)ws_size; (void)n_in; (void)out_size;

    build_rowptr_scan<<<(E + 255) / 256, 256, 0, stream>>>(row, ptr, N, E);

    build_perm_seg<<<(N + PSEG - 1) / PSEG, 1024, 0, stream>>>(ptr, perm, N);

    const int nbG = (N + 127) / 128;
    gemm1_relu<<<nbG, 512, 0, stream>>>(x, W1, b1, ha, na_, N);

    const int nb32 = (N + 31) / 32;     // 32 nodes per 256-thread block
    unsigned short* hc = ha; unsigned short* hn = hb;
    float* nc = na_; float* nn = nb_;
    for (int l = 0; l < 4; ++l) {
        agnn_layer<<<nb32, 256, 0, stream>>>((const uint4*)hc, nc, ptr, col, perm,
                                             (uint4*)hn, nn, N, E);
        unsigned short* t = hc; hc = hn; hn = t;
        float* tf = nc; nc = nn; nn = tf;
    }

    gemm2<<<nbG, 512, 0, stream>>>(hc, nc, W2, b2, out, N);
}

// Round 5
// 298.215 us; speedup vs baseline: 1.1922x; 1.1922x over previous
//
#include <hip/hip_runtime.h>

// ---------------------------------------------------------------------------
// AGNN: h = relu(x@W1^T+b1); 4x [ h = relu(agnn(h)) ]; out = h@W2^T+b2
// N=100000, E=1600000, IN=128, HID=OUT=64, float32 in/out.
// Between layers: xn = h/(||h||+eps) stored FP16 (128 B/row) + nrm f32.
//   p = exp2( dot(xn_i * log2e, xn_j) );  out_i = sum p * nrm_j * xn_j / sum p
// agnn: nodes in SEGMENT-LOCAL degree-sorted order (perm); 4 nodes/wave,
// 16 lanes each, 2 edge-groups x 8 lanes, 2 edges in flight (round-2 body,
// measured 40.6 us/layer).
// Round 5: cross-lane reduces via DPP VALU adds instead of DS shuffles.
//   Round-3/4 analysis: 15.6 cyc/edge = dependency chain dominated by
//   3 ds-shuffle reduces (~90 cyc of ~110 total); loads already hidden
//   (round-3 pipeline was neutral), issue BW not binding (VALU 38%).
//   8-lane sum reduce: quad_perm xor1, xor2, then row_half_mirror (i^7 ==
//   xor4 AFTER quad reduce); group merge of group-uniform den: row_mirror.
//   acc merge keeps exact shfl_xor8 (per-lane distinct, once per node).
// gemm1/gemm2 (512 thr, prefetch), rowptr scan, 1024-seg sort unchanged.
// Round-4 edge-per-lane variant REVERTED (53.8 us: vmcnt(0) serial drain,
// 20% occupancy, bank conflicts).
// ---------------------------------------------------------------------------

typedef _Float16 h2 __attribute__((ext_vector_type(2)));

union U4H { uint4 u; h2 h[4]; };
union U2H { uint2 u; h2 h[2]; };
union UHI { unsigned u; h2 h; };
union UF  { unsigned u; float f; int i; };

#define DEV_INLINE __device__ __forceinline__

DEV_INLINE h2 mkh2(float a, float b) {
    h2 r; r.x = (_Float16)a; r.y = (_Float16)b; return r;
}

// x + dpp_perm(x): CTRL 0xB1 = quad_perm[1,0,3,2] (xor1),
// 0x4E = quad_perm[2,3,0,1] (xor2), 0x141 = row_half_mirror (i^7),
// 0x140 = row_mirror (i^15).  Valid as xor4/xor8 substitutes only inside
// a sum-reduction (after the lower steps have made sub-groups uniform).
template <int CTRL>
DEV_INLINE float dpp_addf(float x) {
    UF a, b;
    a.f = x;
    b.i = __builtin_amdgcn_update_dpp(0, a.i, CTRL, 0xF, 0xF, true);
    return x + b.f;
}

// ptr[i] = lower_bound(row, i). Thread e covers i in (row[e-1], row[e]].
__global__ __launch_bounds__(256) void build_rowptr_scan(const int* __restrict__ row,
                                                         int* __restrict__ ptr,
                                                         int N, int E) {
    int e = blockIdx.x * blockDim.x + threadIdx.x;
    if (e >= E) return;
    const int r1 = row[e];
    const int r0 = (e == 0) ? -1 : row[e - 1];
    for (int i = r0 + 1; i <= r1; ++i) ptr[i] = e;
    if (e == E - 1) {
        for (int i = r1 + 1; i <= N; ++i) ptr[i] = E;
    }
}

// Segment-local counting sort by degree. One 1024-thread block per 1024-node
// segment (1 node per thread); 256-bucket LDS histogram + 8-step scan.
#define PSEG 1024
__global__ __launch_bounds__(1024) void build_perm_seg(const int* __restrict__ ptr,
                                                       int* __restrict__ perm,
                                                       int N) {
    __shared__ int hist[256];
    __shared__ int tmp[256];
    const int t    = threadIdx.x;
    const int base = blockIdx.x * PSEG;
    const int end  = (base + PSEG < N) ? base + PSEG : N;
    const int cnt  = end - base;

    if (t < 256) hist[t] = 0;
    __syncthreads();

    int d = -1;
    if (t < cnt) {
        d = ptr[base + t + 1] - ptr[base + t];
        if (d > 255) d = 255;
        atomicAdd(&hist[d], 1);
    }
    __syncthreads();

    int h0 = (t < 256) ? hist[t] : 0;
    int* src = hist; int* dst = tmp;
    for (int off = 1; off < 256; off <<= 1) {
        if (t < 256) dst[t] = src[t] + (t >= off ? src[t - off] : 0);
        __syncthreads();
        int* tt = src; src = dst; dst = tt;
    }
    if (t < 256) src[t] -= h0;
    __syncthreads();

    if (t < cnt) {
        int pos = base + atomicAdd(&src[d], 1);
        perm[pos] = base + t;
    }
}

// r = relu(x[i,:128]@W1^T + b1); xn[i]=f16(r/(||r||+eps)); nrm[i]=||r||+eps
// 512 threads, tile 128 nodes x 64 outs, thread = 4 nodes x 4 outs.
__global__ __launch_bounds__(512) void gemm1_relu(const float* __restrict__ x,
                                                  const float* __restrict__ W1,
                                                  const float* __restrict__ b1,
                                                  unsigned short* __restrict__ xn,
                                                  float* __restrict__ nrm,
                                                  int N) {
    __shared__ __align__(16) float Wt[32 * 64];    // 8 KiB
    __shared__ __align__(16) float xT[32 * 128];   // 16 KiB
    const int tid  = threadIdx.x;
    const int tx   = tid & 15;
    const int ty   = tid >> 4;
    const int base = blockIdx.x * 128;

    const float4* W4  = (const float4*)W1;
    const float4* x4p = (const float4*)x;

    const int wO  = tid & 63;
    const int wK4 = tid >> 6;
    const int mA  = tid & 127;
    const int kA  = tid >> 7;
    const int mB  = mA;
    const int kB  = kA + 4;
    const int nodeA = base + mA;

    float4 wv, xa_, xb_;
    wv = W4[wO * 32 + wK4];
    xa_ = make_float4(0.f, 0.f, 0.f, 0.f);
    xb_ = xa_;
    if (nodeA < N) {
        xa_ = x4p[(size_t)nodeA * 32 + kA];
        xb_ = x4p[(size_t)nodeA * 32 + kB];
    }

    float4 b4 = ((const float4*)b1)[tx];
    float4 acc[4];
    acc[0] = b4; acc[1] = b4; acc[2] = b4; acc[3] = b4;

    for (int c = 0; c < 4; ++c) {
        Wt[(4 * wK4 + 0) * 64 + wO] = wv.x;
        Wt[(4 * wK4 + 1) * 64 + wO] = wv.y;
        Wt[(4 * wK4 + 2) * 64 + wO] = wv.z;
        Wt[(4 * wK4 + 3) * 64 + wO] = wv.w;
        xT[(4 * kA + 0) * 128 + mA] = xa_.x;
        xT[(4 * kA + 1) * 128 + mA] = xa_.y;
        xT[(4 * kA + 2) * 128 + mA] = xa_.z;
        xT[(4 * kA + 3) * 128 + mA] = xa_.w;
        xT[(4 * kB + 0) * 128 + mB] = xb_.x;
        xT[(4 * kB + 1) * 128 + mB] = xb_.y;
        xT[(4 * kB + 2) * 128 + mB] = xb_.z;
        xT[(4 * kB + 3) * 128 + mB] = xb_.w;
        __syncthreads();

        if (c < 3) {
            const int ko = (c + 1) * 8;
            wv = W4[wO * 32 + ko + wK4];
            if (nodeA < N) {
                xa_ = x4p[(size_t)nodeA * 32 + ko + kA];
                xb_ = x4p[(size_t)nodeA * 32 + ko + kB];
            }
        }

#pragma unroll 4
        for (int k = 0; k < 32; ++k) {
            const float4 w4 = *(const float4*)&Wt[k * 64 + 4 * tx];
            const float4 xv = *(const float4*)&xT[k * 128 + 4 * ty];
            acc[0].x = fmaf(xv.x, w4.x, acc[0].x);
            acc[0].y = fmaf(xv.x, w4.y, acc[0].y);
            acc[0].z = fmaf(xv.x, w4.z, acc[0].z);
            acc[0].w = fmaf(xv.x, w4.w, acc[0].w);
            acc[1].x = fmaf(xv.y, w4.x, acc[1].x);
            acc[1].y = fmaf(xv.y, w4.y, acc[1].y);
            acc[1].z = fmaf(xv.y, w4.z, acc[1].z);
            acc[1].w = fmaf(xv.y, w4.w, acc[1].w);
            acc[2].x = fmaf(xv.z, w4.x, acc[2].x);
            acc[2].y = fmaf(xv.z, w4.y, acc[2].y);
            acc[2].z = fmaf(xv.z, w4.z, acc[2].z);
            acc[2].w = fmaf(xv.z, w4.w, acc[2].w);
            acc[3].x = fmaf(xv.w, w4.x, acc[3].x);
            acc[3].y = fmaf(xv.w, w4.y, acc[3].y);
            acc[3].z = fmaf(xv.w, w4.z, acc[3].z);
            acc[3].w = fmaf(xv.w, w4.w, acc[3].w);
        }
        if (c < 3) __syncthreads();
    }

#pragma unroll
    for (int mm = 0; mm < 4; ++mm) {
        float4 r = acc[mm];
        r.x = fmaxf(r.x, 0.f); r.y = fmaxf(r.y, 0.f);
        r.z = fmaxf(r.z, 0.f); r.w = fmaxf(r.w, 0.f);
        float s = fmaf(r.x, r.x, fmaf(r.y, r.y, fmaf(r.z, r.z, r.w * r.w)));
        // sum over the 16-lane row: xor1, xor2 (quad), i^7, i^15 (valid
        // substitutes for xor4/xor8 inside a sum reduce)
        s = dpp_addf<0xB1>(s);
        s = dpp_addf<0x4E>(s);
        s = dpp_addf<0x141>(s);
        s = dpp_addf<0x140>(s);
        const float nn  = sqrtf(s) + 1e-12f;
        const float inv = 1.f / nn;
        int node = base + 4 * ty + mm;
        if (node < N) {
            U2H pk;
            pk.h[0] = mkh2(r.x * inv, r.y * inv);
            pk.h[1] = mkh2(r.z * inv, r.w * inv);
            *(uint2*)&xn[(size_t)node * 64 + 4 * tx] = pk.u;
            if (tx == mm) nrm[node] = nn;
        }
    }
}

// 4 nodes per wave (16 lanes each, degree-sorted); 2 edge-groups x 8 lanes;
// 2 edges in flight per group.  Cross-lane reduces via DPP.
__global__ __launch_bounds__(256) void agnn_layer(const uint4* __restrict__ xn4,
                                                  const float* __restrict__ nrm,
                                                  const int* __restrict__ ptr,
                                                  const int* __restrict__ col,
                                                  const int* __restrict__ perm,
                                                  uint4* __restrict__ xo4,
                                                  float* __restrict__ nrmo,
                                                  int N) {
    const int tid  = threadIdx.x;
    const int lane = tid & 63;
    const int g    = (lane >> 3) & 1;   // edge group 0..1 within 16-lane quarter
    const int sub  = lane & 7;          // 16B chunk of the 128B row
    const int slot = blockIdx.x * 16 + (tid >> 4);
    if (slot >= N) return;
    const int i = perm[slot];

    U4H hi_;
    hi_.u = xn4[(unsigned)i * 8u + sub];
    {
        const _Float16 L2E = (_Float16)1.4426950408889634f;
        h2 l2 = {L2E, L2E};
#pragma unroll
        for (int t = 0; t < 4; ++t) hi_.h[t] *= l2;   // p = exp2(dot)
    }

    const int p0 = ptr[i], p1 = ptr[i + 1];

    float den = 0.f;
    U4H acc;
    acc.h[0] = mkh2(0.f, 0.f); acc.h[1] = mkh2(0.f, 0.f);
    acc.h[2] = mkh2(0.f, 0.f); acc.h[3] = mkh2(0.f, 0.f);

    // 8-lane sum reduce: xor1, xor2 (quad_perm), then row_half_mirror
    // (i^7 == xor4 once quads are uniform).  ~10 cyc vs ~90 for ds-shuffles.
#define EDGE_BODY(VU, NRMJ)                                                  \
    {                                                                        \
        U4H xa; xa.u = (VU);                                                 \
        float sa = __builtin_amdgcn_fdot2(hi_.h[0], xa.h[0], 0.f, false);    \
        sa = __builtin_amdgcn_fdot2(hi_.h[1], xa.h[1], sa, false);           \
        float sb = __builtin_amdgcn_fdot2(hi_.h[2], xa.h[2], 0.f, false);    \
        sb = __builtin_amdgcn_fdot2(hi_.h[3], xa.h[3], sb, false);           \
        float s = sa + sb;                                                   \
        s = dpp_addf<0xB1>(s);                                               \
        s = dpp_addf<0x4E>(s);                                               \
        s = dpp_addf<0x141>(s);                                              \
        const float p = exp2f(s);                                            \
        den += p;                                                            \
        const _Float16 wh = (_Float16)(p * (NRMJ));                          \
        h2 w2 = {wh, wh};                                                    \
        acc.h[0] += w2 * xa.h[0];                                            \
        acc.h[1] += w2 * xa.h[1];                                            \
        acc.h[2] += w2 * xa.h[2];                                            \
        acc.h[3] += w2 * xa.h[3];                                            \
    }

    int e = p0 + g;
    for (; e + 2 < p1; e += 4) {          // 2 edges per group in flight
        const int ja = col[e];
        const int jb = col[e + 2];
        const uint4 va = xn4[(unsigned)ja * 8u + sub];
        const uint4 vb = xn4[(unsigned)jb * 8u + sub];
        const float na = nrm[ja];
        const float nb = nrm[jb];
        EDGE_BODY(va, na)
        EDGE_BODY(vb, nb)
    }
    if (e < p1) {
        const int j = col[e];
        const uint4 v = xn4[(unsigned)j * 8u + sub];
        const float nj = nrm[j];
        EDGE_BODY(v, nj)
    }
#undef EDGE_BODY

    // merge the 2 edge-groups. den is group-uniform -> row_mirror (i^15
    // lands in the other 8-group). acc is per-lane distinct -> exact xor8.
    {
        den = dpp_addf<0x140>(den);
#pragma unroll
        for (int t = 0; t < 4; ++t) {
            UHI a; a.h = acc.h[t];
            UHI b; b.u = (unsigned)__shfl_xor((int)a.u, 8, 64);
            acc.h[t] = a.h + b.h;
        }
    }

    const float id = 1.f / fmaxf(den, 1e-12f);
    float o[8];
#pragma unroll
    for (int t = 0; t < 4; ++t) {
        o[2 * t]     = fmaxf((float)acc.h[t].x * id, 0.f);
        o[2 * t + 1] = fmaxf((float)acc.h[t].y * id, 0.f);
    }

    float s2 = 0.f;
#pragma unroll
    for (int t = 0; t < 8; ++t) s2 = fmaf(o[t], o[t], s2);
    s2 = dpp_addf<0xB1>(s2);
    s2 = dpp_addf<0x4E>(s2);
    s2 = dpp_addf<0x141>(s2);
    const float nn  = sqrtf(s2) + 1e-12f;
    const float inv = 1.f / nn;

    if (g == 0) {
        U4H ov;
        ov.h[0] = mkh2(o[0] * inv, o[1] * inv);
        ov.h[1] = mkh2(o[2] * inv, o[3] * inv);
        ov.h[2] = mkh2(o[4] * inv, o[5] * inv);
        ov.h[3] = mkh2(o[6] * inv, o[7] * inv);
        xo4[(unsigned)i * 8u + sub] = ov.u;
        if (sub == 0) nrmo[i] = nn;
    }
}

// out[i,:64] = (xn[i]*nrm[i]) @ W2^T + b2   (f32 out)
// 512 threads, tile 128 nodes x 64 outs, thread = 4 nodes x 4 outs.
__global__ __launch_bounds__(512) void gemm2(const unsigned short* __restrict__ xn,
                                             const float* __restrict__ nrm,
                                             const float* __restrict__ W2,
                                             const float* __restrict__ b2,
                                             float* __restrict__ out,
                                             int N) {
    __shared__ __align__(16) float Wt[64 * 64];
    __shared__ __align__(16) float xT[64 * 128];
    const int tid  = threadIdx.x;
    const int tx   = tid & 15;
    const int ty   = tid >> 4;
    const int base = blockIdx.x * 128;

    {
        const float4* W4 = (const float4*)W2;
#pragma unroll
        for (int it = 0; it < 2; ++it) {
            int idx = tid + it * 512;
            int o = idx & 63, k4 = idx >> 6;
            float4 v = W4[o * 16 + k4];
            Wt[(4 * k4 + 0) * 64 + o] = v.x;
            Wt[(4 * k4 + 1) * 64 + o] = v.y;
            Wt[(4 * k4 + 2) * 64 + o] = v.z;
            Wt[(4 * k4 + 3) * 64 + o] = v.w;
        }
        const uint2* x2 = (const uint2*)xn;
#pragma unroll
        for (int it = 0; it < 4; ++it) {
            int idx = tid + it * 512;
            int mm = idx & 127, k4 = idx >> 7;
            int node = base + mm;
            U2H v; v.u = make_uint2(0u, 0u);
            float nn = 0.f;
            if (node < N) { v.u = x2[(size_t)node * 16 + k4]; nn = nrm[node]; }
            xT[(4 * k4 + 0) * 128 + mm] = (float)v.h[0].x * nn;
            xT[(4 * k4 + 1) * 128 + mm] = (float)v.h[0].y * nn;
            xT[(4 * k4 + 2) * 128 + mm] = (float)v.h[1].x * nn;
            xT[(4 * k4 + 3) * 128 + mm] = (float)v.h[1].y * nn;
        }
    }
    __syncthreads();

    float4 b4 = ((const float4*)b2)[tx];
    float4 acc[4];
    acc[0] = b4; acc[1] = b4; acc[2] = b4; acc[3] = b4;

#pragma unroll 4
    for (int k = 0; k < 64; ++k) {
        const float4 w4 = *(const float4*)&Wt[k * 64 + 4 * tx];
        const float4 xv = *(const float4*)&xT[k * 128 + 4 * ty];
        acc[0].x = fmaf(xv.x, w4.x, acc[0].x);
        acc[0].y = fmaf(xv.x, w4.y, acc[0].y);
        acc[0].z = fmaf(xv.x, w4.z, acc[0].z);
        acc[0].w = fmaf(xv.x, w4.w, acc[0].w);
        acc[1].x = fmaf(xv.y, w4.x, acc[1].x);
        acc[1].y = fmaf(xv.y, w4.y, acc[1].y);
        acc[1].z = fmaf(xv.y, w4.z, acc[1].z);
        acc[1].w = fmaf(xv.y, w4.w, acc[1].w);
        acc[2].x = fmaf(xv.z, w4.x, acc[2].x);
        acc[2].y = fmaf(xv.z, w4.y, acc[2].y);
        acc[2].z = fmaf(xv.z, w4.z, acc[2].z);
        acc[2].w = fmaf(xv.z, w4.w, acc[2].w);
        acc[3].x = fmaf(xv.w, w4.x, acc[3].x);
        acc[3].y = fmaf(xv.w, w4.y, acc[3].y);
        acc[3].z = fmaf(xv.w, w4.z, acc[3].z);
        acc[3].w = fmaf(xv.w, w4.w, acc[3].w);
    }

#pragma unroll
    for (int mm = 0; mm < 4; ++mm) {
        int node = base + 4 * ty + mm;
        if (node < N) *(float4*)&out[(size_t)node * 64 + 4 * tx] = acc[mm];
    }
}

extern "C" void kernel_launch(void* const* d_in, const int* in_sizes, int n_in,
                              void* d_out, int out_size, void* d_ws, size_t ws_size,
                              hipStream_t stream) {
    const float* x   = (const float*)d_in[0];
    const int*   row = (const int*)d_in[1];
    const int*   col = (const int*)d_in[2];
    const float* W1  = (const float*)d_in[3];
    const float* b1  = (const float*)d_in[4];
    const float* W2  = (const float*)d_in[5];
    const float* b2  = (const float*)d_in[6];
    float* out = (float*)d_out;

    const int N = in_sizes[0] / 128;
    const int E = in_sizes[1];

    char* ws = (char*)d_ws;
    size_t off = 0;
    unsigned short* ha = (unsigned short*)(ws + off); off += (size_t)N * 64 * 2;
    unsigned short* hb = (unsigned short*)(ws + off); off += (size_t)N * 64 * 2;
    float* na_  = (float*)(ws + off); off += (size_t)N * sizeof(float);
    float* nb_  = (float*)(ws + off); off += (size_t)N * sizeof(float);
    int*   ptr  = (int*)  (ws + off); off += (size_t)(N + 1) * sizeof(int);
    off = (off + 15) & ~(size_t)15;
    int*   perm = (int*)  (ws + off); off += (size_t)N * sizeof(int);
    (void)ws_size; (void)n_in; (void)out_size;

    build_rowptr_scan<<<(E + 255) / 256, 256, 0, stream>>>(row, ptr, N, E);

    build_perm_seg<<<(N + PSEG - 1) / PSEG, 1024, 0, stream>>>(ptr, perm, N);

    const int nbG = (N + 127) / 128;
    gemm1_relu<<<nbG, 512, 0, stream>>>(x, W1, b1, ha, na_, N);

    const int nb16 = (N + 15) / 16;
    unsigned short* hc = ha; unsigned short* hn = hb;
    float* nc = na_; float* nn = nb_;
    for (int l = 0; l < 4; ++l) {
        agnn_layer<<<nb16, 256, 0, stream>>>((const uint4*)hc, nc, ptr, col, perm,
                                             (uint4*)hn, nn, N);
        unsigned short* t = hc; hc = hn; hn = t;
        float* tf = nc; nc = nn; nn = tf;
    }

    gemm2<<<nbG, 512, 0, stream>>>(hc, nc, W2, b2, out, N);
}